// Round 1
// baseline (768.011 us; speedup 1.0000x reference)
//
#include <hip/hip_runtime.h>
#include <hip/hip_bf16.h>

// B=1, H=32, N=T=2048, D=128, R=64
// out[h,n,t] = sum_d q[h,n,d]*kq[h,t,d] + (1/64)*sum_r (q@G)[h,n,r]*sign((ko-kq)@G)[h,t,r]
// Strategy: build augmented bf16 matrices in d_ws:
//   Qb[h][n][0:128]=bf16(q), Qb[h][n][128:192]=bf16(q@G)
//   Kb[h][t][0:128]=bf16(kq), Kb[h][t][128:192]=sign*(1/64)  (exact in bf16)
// then per-head GEMM out = Qb @ Kb^T with K=192 (bf16 MFMA, m97-style).
// ws needed: 2 * 32*2048*192*2 bytes = 50,331,648 bytes.

#define H 32
#define NQ 2048
#define NT 2048
#define D 128
#define R 64
#define KDIM 192

typedef __attribute__((ext_vector_type(4))) float f32x4;
typedef __attribute__((ext_vector_type(8))) short bf16x8;

__device__ __forceinline__ void gl_lds16(const void* g, void* l) {
  __builtin_amdgcn_global_load_lds(
      (const __attribute__((address_space(1))) void*)g,
      (__attribute__((address_space(3))) void*)l, 16, 0, 0);
}

// ---- prep: build Kb rows (4 rows per block, one per wave) ----
__global__ void build_kb(const float* __restrict__ ko, const float* __restrict__ kq,
                         const float* __restrict__ G, __hip_bfloat16* __restrict__ Kb) {
  __shared__ float e_sh[4][D];
  const int wave = threadIdx.x >> 6, lane = threadIdx.x & 63;
  const long row = (long)blockIdx.x * 4 + wave;  // 0 .. H*NT-1
  const float* kor = ko + row * D;
  const float* kqr = kq + row * D;
  float kq0 = kqr[lane], kq1 = kqr[lane + 64];
  e_sh[wave][lane]      = kor[lane]      - kq0;
  e_sh[wave][lane + 64] = kor[lane + 64] - kq1;
  __syncthreads();
  float acc = 0.f;
  const float* e = e_sh[wave];
#pragma unroll 8
  for (int d = 0; d < D; ++d) acc += e[d] * G[d * R + lane];
  __hip_bfloat16* o = Kb + row * KDIM;
  o[lane]      = __float2bfloat16(kq0);
  o[lane + 64] = __float2bfloat16(kq1);
  float sgn = acc > 0.f ? 0.015625f : (acc < 0.f ? -0.015625f : 0.f);
  o[128 + lane] = __float2bfloat16(sgn);
}

// ---- prep: build Qb rows ----
__global__ void build_qb(const float* __restrict__ q, const float* __restrict__ G,
                         __hip_bfloat16* __restrict__ Qb) {
  __shared__ float e_sh[4][D];
  const int wave = threadIdx.x >> 6, lane = threadIdx.x & 63;
  const long row = (long)blockIdx.x * 4 + wave;  // 0 .. H*NQ-1
  const float* qr = q + row * D;
  float q0 = qr[lane], q1 = qr[lane + 64];
  e_sh[wave][lane]      = q0;
  e_sh[wave][lane + 64] = q1;
  __syncthreads();
  float acc = 0.f;
  const float* e = e_sh[wave];
#pragma unroll 8
  for (int d = 0; d < D; ++d) acc += e[d] * G[d * R + lane];
  __hip_bfloat16* o = Qb + row * KDIM;
  o[lane]      = __float2bfloat16(q0);
  o[lane + 64] = __float2bfloat16(q1);
  o[128 + lane] = __float2bfloat16(acc);   // q@G, unscaled (Kb sign carries 1/64)
}

// ---- main GEMM: per head, 2048x2048x192, C = Qb * Kb^T ----
__global__ void gemm_bt(const __hip_bfloat16* __restrict__ Qb,
                        const __hip_bfloat16* __restrict__ Kb,
                        float* __restrict__ out) {
  const int h  = blockIdx.z;
  const int m0 = blockIdx.y * 128;
  const int n0 = blockIdx.x * 128;
  const __hip_bfloat16* A = Qb + (size_t)h * NQ * KDIM;
  const __hip_bfloat16* B = Kb + (size_t)h * NT * KDIM;

  __shared__ __align__(16) __hip_bfloat16 As[128 * 32];  // [row][32] bf16, 64 B/row
  __shared__ __align__(16) __hip_bfloat16 Bs[128 * 32];

  const int tid = threadIdx.x, lane = tid & 63, wave = tid >> 6;
  const int wm = (wave >> 1) * 64, wn = (wave & 1) * 64;
  const int quad = lane >> 4, mrow = lane & 15;

  f32x4 acc[4][4] = {};

  // staging: thread t handles 16B chunk: row = t>>2, byte-in-row = (t&3)*16
  const int srow = tid >> 2;
  const int scol = (tid & 3) * 8;  // element offset (bf16)
  const __hip_bfloat16* gA  = A + (size_t)(m0 + srow) * KDIM + scol;
  const __hip_bfloat16* gA2 = A + (size_t)(m0 + 64 + srow) * KDIM + scol;
  const __hip_bfloat16* gB  = B + (size_t)(n0 + srow) * KDIM + scol;
  const __hip_bfloat16* gB2 = B + (size_t)(n0 + 64 + srow) * KDIM + scol;
  char* lA  = (char*)As + wave * 1024;
  char* lA2 = (char*)As + 4096 + wave * 1024;
  char* lB  = (char*)Bs + wave * 1024;
  char* lB2 = (char*)Bs + 4096 + wave * 1024;

  for (int kt = 0; kt < 6; ++kt) {
    __syncthreads();
    gl_lds16(gA, lA); gl_lds16(gA2, lA2);
    gl_lds16(gB, lB); gl_lds16(gB2, lB2);
    gA += 32; gA2 += 32; gB += 32; gB2 += 32;
    __syncthreads();

    bf16x8 af[4], bfr[4];
#pragma unroll
    for (int i = 0; i < 4; ++i) {
      af[i]  = *(const bf16x8*)((const char*)As + (wm + i * 16 + mrow) * 64 + quad * 16);
      bfr[i] = *(const bf16x8*)((const char*)Bs + (wn + i * 16 + mrow) * 64 + quad * 16);
    }
#pragma unroll
    for (int i = 0; i < 4; ++i)
#pragma unroll
      for (int j = 0; j < 4; ++j)
        acc[i][j] = __builtin_amdgcn_mfma_f32_16x16x32_bf16(af[i], bfr[j], acc[i][j], 0, 0, 0);
  }

  // epilogue: C/D layout col=lane&15, row=quad*4+reg
  float* orow = out + ((size_t)h * NQ + m0) * NT + n0;
#pragma unroll
  for (int i = 0; i < 4; ++i)
#pragma unroll
    for (int r = 0; r < 4; ++r) {
      const int row = wm + i * 16 + quad * 4 + r;
      float* p = orow + (size_t)row * NT + wn + mrow;
#pragma unroll
      for (int j = 0; j < 4; ++j) p[j * 16] = acc[i][j][r];
    }
}

extern "C" void kernel_launch(void* const* d_in, const int* in_sizes, int n_in,
                              void* d_out, int out_size, void* d_ws, size_t ws_size,
                              hipStream_t stream) {
  const float* q  = (const float*)d_in[0];
  const float* ko = (const float*)d_in[1];
  const float* kq = (const float*)d_in[2];
  const float* G  = (const float*)d_in[3];
  float* out = (float*)d_out;

  __hip_bfloat16* Kb = (__hip_bfloat16*)d_ws;
  __hip_bfloat16* Qb = Kb + (size_t)H * NT * KDIM;  // needs 50,331,648 B total

  build_kb<<<(H * NT) / 4, 256, 0, stream>>>(ko, kq, G, Kb);
  build_qb<<<(H * NQ) / 4, 256, 0, stream>>>(q, G, Qb);

  dim3 grid(NT / 128, NQ / 128, H);
  gemm_bt<<<grid, 256, 0, stream>>>(Qb, Kb, out);
}